// Round 9
// baseline (269.429 us; speedup 1.0000x reference)
//
#include <hip/hip_runtime.h>

#define NTOK 4096
#define NBH  32
#define NF   1088     // features: 32 linear + 1024 quadratic + 1 const + 31 pad
#define GTF_BH 52224  // per-bh G elements: 34 kt * 3 rr * 64 lanes * 8

typedef _Float16 half_t;
typedef _Float16 half8 __attribute__((ext_vector_type(8)));
typedef _Float16 half4v __attribute__((ext_vector_type(4)));
typedef _Float16 half2v __attribute__((ext_vector_type(2)));
typedef float f32x4 __attribute__((ext_vector_type(4)));
typedef unsigned int u32;

#define MFMA16(A,B,C) __builtin_amdgcn_mfma_f32_16x16x32_f16((A),(B),(C),0,0,0)

// async 16B global->LDS: lds dst = wave-uniform base + lane*16
#define ASYNC_CP16(dst_lds, src_glb) \
    __builtin_amdgcn_global_load_lds( \
        (const __attribute__((address_space(1))) u32*)(const void*)(src_glb), \
        (__attribute__((address_space(3))) u32*)(void*)(dst_lds), 16, 0, 0)

static __device__ __forceinline__ half8 splat8(half_t x) {
    return (half8){x, x, x, x, x, x, x, x};
}

// fp32x8 -> fp16x8 via packed round-toward-zero converts (4 VALU ops).
// cvt_pkrtz returns __fp16x2; bit_cast to our _Float16x2 (same layout).
static __device__ __forceinline__ half8 cvt8(f32x4 a, f32x4 b) {
    half2v p0 = __builtin_bit_cast(half2v, __builtin_amdgcn_cvt_pkrtz(a[0], a[1]));
    half2v p1 = __builtin_bit_cast(half2v, __builtin_amdgcn_cvt_pkrtz(a[2], a[3]));
    half2v p2 = __builtin_bit_cast(half2v, __builtin_amdgcn_cvt_pkrtz(b[0], b[1]));
    half2v p3 = __builtin_bit_cast(half2v, __builtin_amdgcn_cvt_pkrtz(b[2], b[3]));
    return (half8){p0[0], p0[1], p1[0], p1[1], p2[0], p2[1], p3[0], p3[1]};
}

// ---------------------------------------------------------------------------
// T: transpose + fp32->fp16  k,v [bh][n][32] -> [bh][32][n]
// ---------------------------------------------------------------------------
__global__ __launch_bounds__(256)
void t_kernel(const float* __restrict__ kin, const float* __restrict__ vin,
              half_t* __restrict__ kTg, half_t* __restrict__ vTg)
{
    const int nb = blockIdx.x;     // 16 blocks of 256 n
    const int bh = blockIdx.y;
    const int t  = threadIdx.x;
    __shared__ __align__(16) half_t tile[32 * 272];
    const size_t inbase = ((size_t)bh * NTOK + nb * 256) * 32;

    for (int pass = 0; pass < 2; ++pass) {
        const float* src = pass ? vin : kin;
        half_t* dstg     = pass ? vTg : kTg;
        if (pass) __syncthreads();
        const float4* s4 = (const float4*)(src + inbase);
        #pragma unroll
        for (int r = 0; r < 8; ++r) {
            int f4 = t + 256 * r;
            int n = f4 >> 3, d4 = f4 & 7;
            float4 vv = s4[f4];
            int nn = n ^ ((d4 & 7) << 3);
            int d0 = d4 * 4;
            tile[(d0 + 0) * 272 + nn] = (half_t)vv.x;
            tile[(d0 + 1) * 272 + nn] = (half_t)vv.y;
            tile[(d0 + 2) * 272 + nn] = (half_t)vv.z;
            tile[(d0 + 3) * 272 + nn] = (half_t)vv.w;
        }
        __syncthreads();
        #pragma unroll
        for (int cc = 0; cc < 4; ++cc) {
            int lin = t + 256 * cc;
            int d = lin >> 5, ch = lin & 31;
            int sw = (d >> 2) & 7;
            half8 val = *(const half8*)&tile[d * 272 + ((ch ^ sw) << 3)];
            *(half8*)&dstg[((size_t)bh * 32 + d) * NTOK + nb * 256 + ch * 8] = val;
        }
    }
}

// ---------------------------------------------------------------------------
// A: G[p][e] = sum_n phi(k_n)[p] * [v_n | 1][e]  via f16 MFMA.
// Epilogue: fp32 atomicAdd directly into Gf (b's fragment order) — no P
// planes, no ar kernel. Gf element for feature p, col e:
//   kt=p>>5, qB=(p>>3)&3, j=p&7, rr=e>>4 (e=32 -> rr=2 lane col 0)
//   idx = ((kt*3+rr)*64 + qB*16 + (e&15))*8 + j
// Double-buffered global_load_lds staging, one barrier per stage.
// ---------------------------------------------------------------------------
template<int NMT>
__device__ __forceinline__ void a_body(
    const half_t* __restrict__ kTg, const half_t* __restrict__ vTg,
    float* __restrict__ Gf, int Kc, int bh, int kc, int pw,
    int t, int w, int l16, int quad, half_t* kT0, half_t* vT0)
{
    const half8 h05 = splat8((half_t)0.5f);
    f32x4 acc[NMT][3];
    #pragma unroll
    for (int m = 0; m < NMT; ++m)
        #pragma unroll
        for (int e = 0; e < 3; ++e)
            acc[m][e] = (f32x4){0.f, 0.f, 0.f, 0.f};

    const size_t gbase = (size_t)bh * 32 * NTOK;
    const int nPer = NTOK / Kc;
    const int nStages = nPer >> 7;

    // staging source map (incorporates the chunk-XOR LDS swizzle)
    const int c0 = t,        r0 = c0 >> 4, p0s = (c0 & 15) ^ (r0 & 15);
    const int c1 = 256 + t,  r1 = c1 >> 4, p1s = (c1 & 15) ^ (r1 & 15);

    auto issue = [&](int buf, int nbase) {
        const half_t* gk0 = kTg + gbase + (size_t)r0 * NTOK + nbase + p0s * 8;
        const half_t* gk1 = kTg + gbase + (size_t)r1 * NTOK + nbase + p1s * 8;
        const half_t* gv0 = vTg + gbase + (size_t)r0 * NTOK + nbase + p0s * 8;
        const half_t* gv1 = vTg + gbase + (size_t)r1 * NTOK + nbase + p1s * 8;
        half_t* kb = kT0 + buf * 4096;
        half_t* vb = vT0 + buf * 4096;
        ASYNC_CP16(kb + (size_t)w * 512,        gk0);
        ASYNC_CP16(kb + 2048 + (size_t)w * 512, gk1);
        ASYNC_CP16(vb + (size_t)w * 512,        gv0);
        ASYNC_CP16(vb + 2048 + (size_t)w * 512, gv1);
    };

    issue(0, kc * nPer);

    for (int st = 0; st < nStages; ++st) {
        const int cur = st & 1;
        __syncthreads();   // drains copy(cur); all waves done with buf cur^1
        if (st + 1 < nStages) issue(cur ^ 1, kc * nPer + (st + 1) * 128);
        const half_t* kb = kT0 + cur * 4096;
        const half_t* vb = vT0 + cur * 4096;
        #pragma unroll
        for (int kk = 0; kk < 4; ++kk) {
            const int c = kk * 4 + quad;
            const int shL = ((c ^ l16) << 3);
            half8 kj0 = *(const half8*)&kb[l16 * 128 + shL];
            half8 kj1 = *(const half8*)&kb[(l16 + 16) * 128 + shL];
            half8 bf0 = *(const half8*)&vb[l16 * 128 + shL];
            half8 bf1 = *(const half8*)&vb[(l16 + 16) * 128 + shL];
            half_t onec = (l16 == 0) ? (half_t)1 : (half_t)0;
            half8 bf2 = {onec, onec, onec, onec, onec, onec, onec, onec};
            #pragma unroll
            for (int mt = 0; mt < NMT; ++mt) {
                const int pm = pw + mt * 16;
                half8 af;
                if (pm < 32) {
                    af = pm ? kj1 : kj0;
                } else if (pm == 1056) {
                    af = bf2;                       // const feature row
                } else if (pm > 1056) {
                    continue;                       // pad tiles
                } else {
                    const int i = (pm - 32) >> 5;
                    const int j0 = (pm - 32) & 31;
                    half8 ki = *(const half8*)&kb[i * 128 + ((c ^ (i & 15)) << 3)];
                    ki = ki * h05;
                    af = ki * (j0 ? kj1 : kj0);
                }
                acc[mt][0] = MFMA16(af, bf0, acc[mt][0]);
                acc[mt][1] = MFMA16(af, bf1, acc[mt][1]);
                acc[mt][2] = MFMA16(af, bf2, acc[mt][2]);
            }
        }
    }

    float* Gb = Gf + (size_t)bh * GTF_BH;
    #pragma unroll
    for (int mt = 0; mt < NMT; ++mt) {
        const int pm = pw + mt * 16;
        if (pm > 1056) continue;
        const int pbase = pm + quad * 4;
        const int kt = pbase >> 5;
        const int qB = (pbase >> 3) & 3;
        const int j0 = pbase & 7;
        float* d0 = &Gb[((size_t)(kt * 3 + 0) * 64 + qB * 16 + l16) * 8 + j0];
        float* d1 = &Gb[((size_t)(kt * 3 + 1) * 64 + qB * 16 + l16) * 8 + j0];
        #pragma unroll
        for (int r = 0; r < 4; ++r) {
            atomicAdd(d0 + r, acc[mt][0][r]);
            atomicAdd(d1 + r, acc[mt][1][r]);
        }
        if (l16 == 0) {
            float* d2 = &Gb[((size_t)(kt * 3 + 2) * 64 + qB * 16 + 0) * 8 + j0];
            #pragma unroll
            for (int r = 0; r < 4; ++r) atomicAdd(d2 + r, acc[mt][2][r]);
        }
    }
}

__global__ __launch_bounds__(256, 2)
void a_kernel(const half_t* __restrict__ kTg, const half_t* __restrict__ vTg,
              float* __restrict__ Gf, int Kc)
{
    const int x  = blockIdx.x;
    const int bh = x & (NBH - 1);
    const int kc = x >> 5;
    const int half = blockIdx.y;   // 0: feats 0..575, 1: 576..1087
    const int t = threadIdx.x;
    const int w = t >> 6, lane = t & 63, l16 = lane & 15, quad = lane >> 4;

    __shared__ __align__(16) half_t kT[2 * 4096];
    __shared__ __align__(16) half_t vT[2 * 4096];

    if (half == 0) {
        a_body<9>(kTg, vTg, Gf, Kc, bh, kc, w * 144, t, w, l16, quad, kT, vT);
    } else {
        a_body<8>(kTg, vTg, Gf, Kc, bh, kc, 576 + w * 128, t, w, l16, quad, kT, vT);
    }
}

// ---------------------------------------------------------------------------
// B: out[n][e] = (phi(q_n).G[:,e]) / (phi(q_n).G[:,32]) via f16 MFMA.
// Gf fragments are lane-dense fp32 (2KB/wave/load), depth-3 register ring,
// cvt_pkrtz to fp16 at consumption. kt=33 carries the const feature.
// Flat grid with XCD swizzle: bh = (blk&7) + 8*((blk>>3)&3) -> all 16
// blocks of one bh land on one XCD -> Gf L2-resident after first touch.
// ---------------------------------------------------------------------------
__global__ __launch_bounds__(256)
void b_kernel(const float* __restrict__ qin, const float* __restrict__ Gf,
              float* __restrict__ out)
{
    const int blk = blockIdx.x;
    const int s = blk >> 3;
    const int bh = (blk & 7) + 8 * (s & 3);
    const int mbq = s >> 2;
    const int t = threadIdx.x, w = t >> 6, lane = t & 63;
    const int l16 = lane & 15, quad = lane >> 4;
    __shared__ __align__(16) half_t qs[256 * 40];
    __shared__ __align__(16) half_t qsP[32 * 272];  // [i][w][l16][mt]
    __shared__ float denl[256];
    const size_t nbase = (size_t)bh * NTOK + mbq * 256;

    const float4* q4 = (const float4*)(qin + nbase * 32);
    #pragma unroll
    for (int r = 0; r < 8; ++r) {
        int f4 = t + 256 * r, n = f4 >> 3, d4 = f4 & 7;
        float4 vv = q4[f4];
        half4v h = {(half_t)vv.x, (half_t)vv.y, (half_t)vv.z, (half_t)vv.w};
        *(half4v*)&qs[n * 40 + d4 * 4] = h;
        int pb = (n >> 6) * 64 + (n & 15) * 4 + ((n >> 4) & 3);
        qsP[(4 * d4 + 0) * 272 + pb] = h[0];
        qsP[(4 * d4 + 1) * 272 + pb] = h[1];
        qsP[(4 * d4 + 2) * 272 + pb] = h[2];
        qsP[(4 * d4 + 3) * 272 + pb] = h[3];
    }
    __syncthreads();

    const int rbase = w * 64;
    half8 vq[4];
    #pragma unroll
    for (int mt = 0; mt < 4; ++mt)
        vq[mt] = *(const half8*)&qs[(rbase + mt * 16 + l16) * 40 + quad * 8];

    f32x4 acc[3][4];
    #pragma unroll
    for (int a = 0; a < 3; ++a)
        #pragma unroll
        for (int b = 0; b < 4; ++b)
            acc[a][b] = (f32x4){0.f, 0.f, 0.f, 0.f};

    const float* Gb = Gf + (size_t)bh * GTF_BH + (size_t)lane * 8;
    const int sOff = w * 64 + l16 * 4;

#define LDF(kt, B) do { \
    _Pragma("unroll") \
    for (int rr = 0; rr < 3; ++rr) { \
        (B)[rr][0] = *(const f32x4*)&Gb[(size_t)(((kt) * 3 + rr) * 64) * 8]; \
        (B)[rr][1] = *(const f32x4*)&Gb[(size_t)(((kt) * 3 + rr) * 64) * 8 + 4]; \
    } \
} while (0)

    f32x4 B0[3][2], B1[3][2], B2[3][2], B3[3][2];
    LDF(0, B0); LDF(1, B1); LDF(2, B2);

    // kt = 0: linear features, af = vq
    {
        LDF(3, B3);
        half8 c0 = cvt8(B0[0][0], B0[0][1]);
        half8 c1 = cvt8(B0[1][0], B0[1][1]);
        half8 c2 = cvt8(B0[2][0], B0[2][1]);
        #pragma unroll
        for (int mt = 0; mt < 4; ++mt) {
            acc[0][mt] = MFMA16(vq[mt], c0, acc[0][mt]);
            acc[1][mt] = MFMA16(vq[mt], c1, acc[1][mt]);
            acc[2][mt] = MFMA16(vq[mt], c2, acc[2][mt]);
        }
        #pragma unroll
        for (int rr = 0; rr < 3; ++rr)
            #pragma unroll
            for (int h = 0; h < 2; ++h) { B0[rr][h] = B1[rr][h]; B1[rr][h] = B2[rr][h]; B2[rr][h] = B3[rr][h]; }
    }
    // kt = 1..32: quadratic features, af = q_i * vq
    #pragma unroll 1
    for (int kt = 1; kt <= 32; ++kt) {
        const int ktp = (kt + 3 <= 33) ? kt + 3 : 33;
        LDF(ktp, B3);
        half4v sv = *(const half4v*)&qsP[(kt - 1) * 272 + sOff];
        half8 c0 = cvt8(B0[0][0], B0[0][1]);
        half8 c1 = cvt8(B0[1][0], B0[1][1]);
        half8 c2 = cvt8(B0[2][0], B0[2][1]);
        half8 af[4];
        #pragma unroll
        for (int mt = 0; mt < 4; ++mt)
            af[mt] = vq[mt] * splat8(sv[mt]);
        #pragma unroll
        for (int mt = 0; mt < 4; ++mt) {
            acc[0][mt] = MFMA16(af[mt], c0, acc[0][mt]);
            acc[1][mt] = MFMA16(af[mt], c1, acc[1][mt]);
            acc[2][mt] = MFMA16(af[mt], c2, acc[2][mt]);
        }
        #pragma unroll
        for (int rr = 0; rr < 3; ++rr)
            #pragma unroll
            for (int h = 0; h < 2; ++h) { B0[rr][h] = B1[rr][h]; B1[rr][h] = B2[rr][h]; B2[rr][h] = B3[rr][h]; }
    }
    // kt = 33: const feature at p=1056: af = e0 on quad 0
    {
        half8 cf = {};
        if (quad == 0) cf[0] = (half_t)1;
        half8 c0 = cvt8(B0[0][0], B0[0][1]);
        half8 c1 = cvt8(B0[1][0], B0[1][1]);
        half8 c2 = cvt8(B0[2][0], B0[2][1]);
        #pragma unroll
        for (int mt = 0; mt < 4; ++mt) {
            acc[0][mt] = MFMA16(cf, c0, acc[0][mt]);
            acc[1][mt] = MFMA16(cf, c1, acc[1][mt]);
            acc[2][mt] = MFMA16(cf, c2, acc[2][mt]);
        }
    }
#undef LDF

    // broadcast den (col 32 lives in l16==0 lanes of acc[2]) via LDS
    if (l16 == 0) {
        #pragma unroll
        for (int mt = 0; mt < 4; ++mt)
            #pragma unroll
            for (int r = 0; r < 4; ++r)
                denl[rbase + mt * 16 + quad * 4 + r] = acc[2][mt][r];
    }
    __syncthreads();
    #pragma unroll
    for (int mt = 0; mt < 4; ++mt) {
        float inv[4];
        #pragma unroll
        for (int r = 0; r < 4; ++r)
            inv[r] = __builtin_amdgcn_rcpf(denl[rbase + mt * 16 + quad * 4 + r]);
        #pragma unroll
        for (int r = 0; r < 4; ++r) {
            size_t ro = (nbase + rbase + mt * 16 + quad * 4 + r) * 32;
            out[ro + l16] = acc[0][mt][r] * inv[r];
            out[ro + l16 + 16] = acc[1][mt][r] * inv[r];
        }
    }
}

// ---------------------------------------------------------------------------
extern "C" void kernel_launch(void* const* d_in, const int* in_sizes, int n_in,
                              void* d_out, int out_size, void* d_ws, size_t ws_size,
                              hipStream_t stream)
{
    const float* q = (const float*)d_in[0];
    const float* k = (const float*)d_in[1];
    const float* v = (const float*)d_in[2];
    float* out = (float*)d_out;

    const size_t gfBytes = (size_t)NBH * GTF_BH * 4;       // 6,684,672
    const int Kc = 8;

    float* Gf  = (float*)d_ws;
    half_t* kTg = (half_t*)((char*)d_ws + gfBytes);
    half_t* vTg = kTg + (size_t)NBH * 32 * NTOK;
    (void)ws_size;

    (void)hipMemsetAsync(Gf, 0, gfBytes, stream);
    t_kernel<<<dim3(16, NBH), 256, 0, stream>>>(k, v, kTg, vTg);
    a_kernel<<<dim3(Kc * NBH, 2), 256, 0, stream>>>(kTg, vTg, Gf, Kc);
    b_kernel<<<512, 256, 0, stream>>>(q, Gf, out);
}